// Round 5
// baseline (5254.710 us; speedup 1.0000x reference)
//
#include <hip/hip_runtime.h>
#include <hip/hip_bf16.h>
#include <cstdint>

typedef __bf16 bf16_t;
typedef __bf16 bf16x8 __attribute__((ext_vector_type(8)));
typedef float f32x4 __attribute__((ext_vector_type(4)));

#define BB 8
#define TT 2048
#define TC 512             // chunk length (4 chunks)
#define TCLOG 9
#define NCHUNK 4
#define MCH (BB*TC)        // 4096 local rows per chunk
#define CCH 1024
#define HH 16
#define HSZ 64
#define LR5 160            // 5 * LORA_R
#define TDR 64

// ---------------- f32 -> bf16 convert ----------------
__global__ __launch_bounds__(256) void f2b_kernel(const float* __restrict__ in,
        bf16_t* __restrict__ out, int n) {
    int i = blockIdx.x * 256 + threadIdx.x;
    if (i < n) out[i] = (bf16_t)in[i];
}

// ---------------- transpose + convert: (R,Cc) f32 -> (Cc,R) bf16 ----------------
__global__ __launch_bounds__(256) void transb_kernel(const float* __restrict__ in,
        bf16_t* __restrict__ out, int R, int Cc) {
    int i = blockIdx.x * 256 + threadIdx.x;
    if (i >= R * Cc) return;
    int r = i / Cc, c = i - r * Cc;
    out[c * R + r] = (bf16_t)in[i];
}

// ---------------- xm = x + (x_prev - x) * miu_x   (f32 in, bf16 out, chunk rows) ----------------
__global__ __launch_bounds__(256) void xm_kernel(const float* __restrict__ x,
        const float* __restrict__ miu_x, bf16_t* __restrict__ xm, int cOff) {
    long long i = (long long)blockIdx.x * 256 + threadIdx.x;   // over MCH*CCH
    int ch = (int)(i & (CCH - 1));
    int btl = (int)(i >> 10);                 // local row in [0, MCH)
    int b = btl >> TCLOG, tau = btl & (TC - 1);
    int t = cOff + tau;
    size_t gi = ((size_t)b * TT + t) * CCH + ch;
    float xv = x[gi];
    float xp = (t > 0) ? x[gi - CCH] : 0.f;
    xm[i] = (bf16_t)(xv + (xp - xv) * miu_x[ch]);
}

// ---------------- xx_f = x + dxa * (lambda_f + lora_h_f @ B_lora_f)  (f32 in, bf16 out) ----------------
__global__ __launch_bounds__(256) void xx_kernel(const float* __restrict__ x,
        const float* __restrict__ lambda_, const bf16_t* __restrict__ lora_h,
        const float* __restrict__ B_lora, int f, bf16_t* __restrict__ xx, int cOff) {
    int btl = blockIdx.x;                     // local token row
    int b = btl >> TCLOG, tau = btl & (TC - 1);
    int t = cOff + tau;
    __shared__ float lhs[32];
    if (threadIdx.x < 32) lhs[threadIdx.x] = (float)lora_h[(size_t)btl * LR5 + f * 32 + threadIdx.x];
    __syncthreads();
    const float* Bf = B_lora + (size_t)f * 32 * CCH;
    size_t gbase = ((size_t)b * TT + t) * CCH;
    size_t lbase = (size_t)btl * CCH;
    #pragma unroll
    for (int q = 0; q < 4; ++q) {
        int c = threadIdx.x + q * 256;
        float xv = x[gbase + c];
        float xp = (t > 0) ? x[gbase + c - CCH] : 0.f;
        float miu = lambda_[f * CCH + c];
        #pragma unroll
        for (int ii = 0; ii < 32; ++ii)
            miu += lhs[ii] * Bf[ii * CCH + c];
        xx[lbase + c] = (bf16_t)(xv + (xp - xv) * miu);
    }
}

// ---------------- w = td_miu + td_h @ td_B  (f32 out; exp in scan) ----------------
__global__ __launch_bounds__(256) void wcomp_kernel(const bf16_t* __restrict__ td_h,
        const float* __restrict__ td_B, const float* __restrict__ td_miu,
        float* __restrict__ wout) {
    int btl = blockIdx.x;
    __shared__ float th[TDR];
    if (threadIdx.x < TDR) th[threadIdx.x] = (float)td_h[(size_t)btl * TDR + threadIdx.x];
    __syncthreads();
    #pragma unroll
    for (int q = 0; q < 4; ++q) {
        int c = threadIdx.x + q * 256;
        float acc = td_miu[c];
        #pragma unroll 8
        for (int jj = 0; jj < TDR; ++jj)
            acc += th[jj] * td_B[jj * CCH + c];
        wout[(size_t)btl * CCH + c] = acc;
    }
}

// ---------------- MFMA GEMM: out[m,n] = sum_k A[m,k]*Bw[n,k]; optional chunk->global C rows ----------------
#define BM 128
#define BN 128
#define BKK 64
#define LDSK 72   // BKK + 8 bf16 pad

enum { EPI_NONE = 0, EPI_SILU = 1, EPI_TANH = 2 };

template<int EPI, bool CMAP, typename OutT>
__global__ __launch_bounds__(256) void gemm_bt(const bf16_t* __restrict__ A,
        const bf16_t* __restrict__ Bw, OutT* __restrict__ Cm,
        int N, int K, int ldc, int cOff) {
    __shared__ __align__(16) bf16_t As[BM * LDSK];
    __shared__ __align__(16) bf16_t Bs[BN * LDSK];
    const int m0 = blockIdx.x * BM;
    const int n0 = blockIdx.y * BN;
    const int tid = threadIdx.x;
    const int w = tid >> 6, lane = tid & 63;
    const int wm = (w >> 1) * 64, wn = (w & 1) * 64;  // 2x2 waves, 64x64 each
    const int lrow = lane & 15;
    const int kq = (lane >> 4) * 8;
    f32x4 acc[4][4] = {};
    for (int k0 = 0; k0 < K; k0 += BKK) {
        __syncthreads();
        #pragma unroll
        for (int p = 0; p < 4; ++p) {
            int chunk = tid + p * 256;
            int row = chunk >> 3;
            int c8 = (chunk & 7) * 8;
            uint4 av = *(const uint4*)(A + (size_t)(m0 + row) * K + k0 + c8);
            *(uint4*)(&As[row * LDSK + c8]) = av;
            int n = n0 + row;
            uint4 bv = make_uint4(0u, 0u, 0u, 0u);
            if (n < N) bv = *(const uint4*)(Bw + (size_t)n * K + k0 + c8);
            *(uint4*)(&Bs[row * LDSK + c8]) = bv;
        }
        __syncthreads();
        #pragma unroll
        for (int kk = 0; kk < BKK; kk += 32) {
            bf16x8 af[4], bfr[4];
            #pragma unroll
            for (int mt = 0; mt < 4; ++mt)
                af[mt] = *(const bf16x8*)(&As[(wm + mt * 16 + lrow) * LDSK + kk + kq]);
            #pragma unroll
            for (int nt = 0; nt < 4; ++nt)
                bfr[nt] = *(const bf16x8*)(&Bs[(wn + nt * 16 + lrow) * LDSK + kk + kq]);
            #pragma unroll
            for (int mt = 0; mt < 4; ++mt)
                #pragma unroll
                for (int nt = 0; nt < 4; ++nt)
                    acc[mt][nt] = __builtin_amdgcn_mfma_f32_16x16x32_bf16(
                        af[mt], bfr[nt], acc[mt][nt], 0, 0, 0);
        }
    }
    // C/D layout: col = lane&15, row = (lane>>4)*4 + reg  [verified m89/m91]
    const int rbase = (lane >> 4) * 4;
    const int col = lane & 15;
    #pragma unroll
    for (int mt = 0; mt < 4; ++mt) {
        #pragma unroll
        for (int nt = 0; nt < 4; ++nt) {
            int n = n0 + wn + nt * 16 + col;
            if (n >= N) continue;
            #pragma unroll
            for (int rg = 0; rg < 4; ++rg) {
                int m = m0 + wm + mt * 16 + rbase + rg;
                size_t mg = CMAP ? ((size_t)(m >> TCLOG) * TT + cOff + (m & (TC - 1)))
                                 : (size_t)m;
                float vv = acc[mt][nt][rg];
                if (EPI == EPI_SILU) vv = vv / (1.f + expf(-vv));
                else if (EPI == EPI_TANH) vv = tanhf(vv);
                Cm[mg * ldc + n] = (OutT)vv;
            }
        }
    }
}

// ---------------- WKV6 scan chunk: one wave per (b,h); y written IN-PLACE over r ----------------
__global__ __launch_bounds__(64) void wkv_kernel(bf16_t* ry,
        const bf16_t* __restrict__ k, const bf16_t* __restrict__ v,
        const float* __restrict__ w, const float* __restrict__ u,
        float* state, int c) {
    const int bh = blockIdx.x;
    const int b = bh >> 4, h = bh & 15;
    const int j = threadIdx.x;
    const size_t base = (size_t)b * TC * CCH + h * HSZ + j;
    float* st = state + (size_t)bh * HSZ * HSZ;
    float S[HSZ];
    if (c > 0) {
        #pragma unroll
        for (int i = 0; i < HSZ; ++i) S[i] = st[i * HSZ + j];
    } else {
        #pragma unroll
        for (int i = 0; i < HSZ; ++i) S[i] = 0.f;
    }
    __shared__ float4 lds[HSZ];
    const float uj = u[h * HSZ + j];
    float rv = (float)ry[base], kv = (float)k[base], vv = (float)v[base];
    float wv = w[base];
    for (int t = 0; t < TC; ++t) {
        float dv = expf(-expf(wv));
        __syncthreads();
        lds[j] = make_float4(rv, kv, dv, rv * uj * kv);
        __syncthreads();
        float nrv = 0.f, nkv = 0.f, nvv = 0.f, nwv = 0.f;
        if (t + 1 < TC) {
            size_t ni = base + (size_t)(t + 1) * CCH;
            nrv = (float)ry[ni]; nkv = (float)k[ni]; nvv = (float)v[ni]; nwv = w[ni];
        }
        float yy = 0.f, aa = 0.f;
        #pragma unroll
        for (int i = 0; i < HSZ; ++i) {
            float4 p = lds[i];          // broadcast read, conflict-free
            yy += p.x * S[i];           // y uses pre-update S
            aa += p.w;                  // sum_i r_i*u_i*k_i
            S[i] = p.z * S[i] + p.y * vv;
        }
        ry[base + (size_t)t * CCH] = (bf16_t)(yy + aa * vv);
        rv = nrv; kv = nkv; vv = nvv; wv = nwv;
    }
    #pragma unroll
    for (int i = 0; i < HSZ; ++i) st[i * HSZ + j] = S[i];
}

// ---------------- GroupNorm(16 groups of 64) * g, in-place on y chunk ----------------
__global__ __launch_bounds__(256) void gn_kernel(bf16_t* yg,
        const float* __restrict__ g_glob, const float* __restrict__ gamma,
        const float* __restrict__ beta, int cOff) {
    int wave = threadIdx.x >> 6, lane = threadIdx.x & 63;
    int gid = blockIdx.x * 4 + wave;          // over MCH*HH
    int h = gid & (HH - 1);
    int ml = gid >> 4;                        // local token row
    int b = ml >> TCLOG, tau = ml & (TC - 1);
    size_t lidx = (size_t)ml * CCH + h * HSZ + lane;
    size_t gidx = ((size_t)b * TT + cOff + tau) * CCH + h * HSZ + lane;
    float val = (float)yg[lidx];
    float s = val, s2 = val * val;
    #pragma unroll
    for (int off = 32; off > 0; off >>= 1) {
        s  += __shfl_xor(s, off);
        s2 += __shfl_xor(s2, off);
    }
    float mean = s * (1.f / HSZ);
    float var  = fmaxf(s2 * (1.f / HSZ) - mean * mean, 0.f);
    float inv  = rsqrtf(var + 1e-5f * HH);
    float yn = (val - mean) * inv * gamma[h * HSZ + lane] + beta[h * HSZ + lane];
    yg[lidx] = (bf16_t)(yn * g_glob[gidx]);
}

extern "C" void kernel_launch(void* const* d_in, const int* in_sizes, int n_in,
                              void* d_out, int out_size, void* d_ws, size_t ws_size,
                              hipStream_t stream) {
    const float* x       = (const float*)d_in[0];
    const float* miu_x   = (const float*)d_in[1];
    const float* lambda_ = (const float*)d_in[2];
    const float* A_lora  = (const float*)d_in[3];
    const float* B_lora  = (const float*)d_in[4];
    const float* td_miu  = (const float*)d_in[5];
    const float* td_A    = (const float*)d_in[6];
    const float* td_B    = (const float*)d_in[7];
    const float* u       = (const float*)d_in[8];
    const float* Wr      = (const float*)d_in[9];
    const float* Wk      = (const float*)d_in[10];
    const float* Wv      = (const float*)d_in[11];
    const float* Wg      = (const float*)d_in[12];
    const float* Wo      = (const float*)d_in[13];
    const float* gamma   = (const float*)d_in[14];
    const float* beta    = (const float*)d_in[15];
    float* out = (float*)d_out;

    // ---- workspace carve-up: ~63 MiB total ----
    char* ws = (char*)d_ws;
    size_t off = 0;
    auto alloc = [&](size_t bytes) {
        char* p = ws + off;
        off += (bytes + 255) & ~(size_t)255;
        return (void*)p;
    };
    const size_t MCC = (size_t)MCH * CCH;               // 4M elems per chunk buffer
    bf16_t* xxc  = (bf16_t*)alloc(MCC * 2);             // xm / xx scratch (reused)
    bf16_t* kc   = (bf16_t*)alloc(MCC * 2);
    bf16_t* vc   = (bf16_t*)alloc(MCC * 2);
    float*  wc   = (float*)alloc(MCC * 4);              // f32: decay-compounding sensitivity
    bf16_t* ryc  = (bf16_t*)alloc(MCC * 2);             // r chunk, then y, then yn*g
    bf16_t* lhc  = (bf16_t*)alloc((size_t)MCH * LR5 * 2);
    bf16_t* tdhc = (bf16_t*)alloc((size_t)MCH * TDR * 2);
    bf16_t* At   = (bf16_t*)alloc((size_t)LR5 * CCH * 2);
    bf16_t* tdAt = (bf16_t*)alloc((size_t)TDR * CCH * 2);
    bf16_t* Wb[5];
    for (int i = 0; i < 5; ++i) Wb[i] = (bf16_t*)alloc((size_t)CCH * CCH * 2);
    float*  state = (float*)alloc((size_t)BB * HH * HSZ * HSZ * 4);  // 2 MB S checkpoint
    (void)ws_size; (void)in_sizes; (void)n_in; (void)out_size;
    bf16_t* Wrb = Wb[0]; bf16_t* Wkb = Wb[1]; bf16_t* Wvb = Wb[2];
    bf16_t* Wgb = Wb[3]; bf16_t* Wob = Wb[4];

    // weight prep: Wx are already [n,k] (reference does x @ W.T) -> convert only
    const int WN = CCH * CCH;
    f2b_kernel<<<(WN + 255) / 256, 256, 0, stream>>>(Wr, Wrb, WN);
    f2b_kernel<<<(WN + 255) / 256, 256, 0, stream>>>(Wk, Wkb, WN);
    f2b_kernel<<<(WN + 255) / 256, 256, 0, stream>>>(Wv, Wvb, WN);
    f2b_kernel<<<(WN + 255) / 256, 256, 0, stream>>>(Wg, Wgb, WN);
    f2b_kernel<<<(WN + 255) / 256, 256, 0, stream>>>(Wo, Wob, WN);
    // A_lora (C x 160) and td_A (C x 64) -> transpose+convert to [n,k]
    transb_kernel<<<(CCH * LR5 + 255) / 256, 256, 0, stream>>>(A_lora, At, CCH, LR5);
    transb_kernel<<<(CCH * TDR + 255) / 256, 256, 0, stream>>>(td_A, tdAt, CCH, TDR);

    for (int c = 0; c < NCHUNK; ++c) {
        const int cOff = c * TC;
        // lora_h for this chunk
        xm_kernel<<<MCC / 256, 256, 0, stream>>>(x, miu_x, xxc, cOff);
        gemm_bt<EPI_TANH, false, bf16_t><<<dim3(MCH / BM, 2), 256, 0, stream>>>(
            xxc, At, lhc, LR5, CCH, LR5, 0);
        // w branch
        xx_kernel<<<MCH, 256, 0, stream>>>(x, lambda_, lhc, B_lora, 0, xxc, cOff);
        gemm_bt<EPI_TANH, false, bf16_t><<<dim3(MCH / BM, 1), 256, 0, stream>>>(
            xxc, tdAt, tdhc, TDR, CCH, TDR, 0);
        wcomp_kernel<<<MCH, 256, 0, stream>>>(tdhc, td_B, td_miu, wc);
        // k, v branches
        xx_kernel<<<MCH, 256, 0, stream>>>(x, lambda_, lhc, B_lora, 1, xxc, cOff);
        gemm_bt<EPI_NONE, false, bf16_t><<<dim3(MCH / BM, CCH / BN), 256, 0, stream>>>(
            xxc, Wkb, kc, CCH, CCH, CCH, 0);
        xx_kernel<<<MCH, 256, 0, stream>>>(x, lambda_, lhc, B_lora, 2, xxc, cOff);
        gemm_bt<EPI_NONE, false, bf16_t><<<dim3(MCH / BM, CCH / BN), 256, 0, stream>>>(
            xxc, Wvb, vc, CCH, CCH, CCH, 0);
        // g branch -> parked f32 in d_out (global rows of this chunk) until GroupNorm
        xx_kernel<<<MCH, 256, 0, stream>>>(x, lambda_, lhc, B_lora, 4, xxc, cOff);
        gemm_bt<EPI_SILU, true, float><<<dim3(MCH / BM, CCH / BN), 256, 0, stream>>>(
            xxc, Wgb, out, CCH, CCH, CCH, cOff);
        // r branch
        xx_kernel<<<MCH, 256, 0, stream>>>(x, lambda_, lhc, B_lora, 3, xxc, cOff);
        gemm_bt<EPI_NONE, false, bf16_t><<<dim3(MCH / BM, CCH / BN), 256, 0, stream>>>(
            xxc, Wrb, ryc, CCH, CCH, CCH, 0);
        // scan this chunk: y overwrites r in-place; S checkpointed across chunks
        wkv_kernel<<<BB * HH, 64, 0, stream>>>(ryc, kc, vc, wc, u, state, c);
        // groupnorm * g (reads g rows from d_out, in-place on y), then Wo projection (f32 out)
        gn_kernel<<<(MCH * HH) / 4, 256, 0, stream>>>(ryc, out, gamma, beta, cOff);
        gemm_bt<EPI_NONE, true, float><<<dim3(MCH / BM, CCH / BN), 256, 0, stream>>>(
            ryc, Wob, out, CCH, CCH, CCH, cOff);
    }
}

// Round 6
// 2786.000 us; speedup vs baseline: 1.8861x; 1.8861x over previous
//
#include <hip/hip_runtime.h>
#include <hip/hip_bf16.h>
#include <cstdint>

typedef __bf16 bf16_t;
typedef __bf16 bf16x8 __attribute__((ext_vector_type(8)));
typedef float f32x4 __attribute__((ext_vector_type(4)));

#define BB 8
#define TT 2048
#define TC 512             // outer chunk length (4 chunks)
#define TCLOG 9
#define NCHUNK 4
#define MCH (BB*TC)        // 4096 local rows per chunk
#define CCH 1024
#define HH 16
#define HSZ 64
#define LR5 160            // 5 * LORA_R
#define TDR 64
#define TSUB 64            // scan sub-chunk length
#define NSC (TC/TSUB)      // 8 sub-chunks per outer chunk
#define BBHH (BB*HH)       // 128

// ---------------- f32 -> bf16 convert ----------------
__global__ __launch_bounds__(256) void f2b_kernel(const float* __restrict__ in,
        bf16_t* __restrict__ out, int n) {
    int i = blockIdx.x * 256 + threadIdx.x;
    if (i < n) out[i] = (bf16_t)in[i];
}

// ---------------- transpose + convert: (R,Cc) f32 -> (Cc,R) bf16 ----------------
__global__ __launch_bounds__(256) void transb_kernel(const float* __restrict__ in,
        bf16_t* __restrict__ out, int R, int Cc) {
    int i = blockIdx.x * 256 + threadIdx.x;
    if (i >= R * Cc) return;
    int r = i / Cc, c = i - r * Cc;
    out[c * R + r] = (bf16_t)in[i];
}

// ---------------- xm = x + (x_prev - x) * miu_x   (f32 in, bf16 out, chunk rows) ----------------
__global__ __launch_bounds__(256) void xm_kernel(const float* __restrict__ x,
        const float* __restrict__ miu_x, bf16_t* __restrict__ xm, int cOff) {
    long long i = (long long)blockIdx.x * 256 + threadIdx.x;   // over MCH*CCH
    int ch = (int)(i & (CCH - 1));
    int btl = (int)(i >> 10);                 // local row in [0, MCH)
    int b = btl >> TCLOG, tau = btl & (TC - 1);
    int t = cOff + tau;
    size_t gi = ((size_t)b * TT + t) * CCH + ch;
    float xv = x[gi];
    float xp = (t > 0) ? x[gi - CCH] : 0.f;
    xm[i] = (bf16_t)(xv + (xp - xv) * miu_x[ch]);
}

// ---------------- xx_f = x + dxa * (lambda_f + lora_h_f @ B_lora_f)  (f32 in, bf16 out) ----------------
__global__ __launch_bounds__(256) void xx_kernel(const float* __restrict__ x,
        const float* __restrict__ lambda_, const bf16_t* __restrict__ lora_h,
        const float* __restrict__ B_lora, int f, bf16_t* __restrict__ xx, int cOff) {
    int btl = blockIdx.x;                     // local token row
    int b = btl >> TCLOG, tau = btl & (TC - 1);
    int t = cOff + tau;
    __shared__ float lhs[32];
    if (threadIdx.x < 32) lhs[threadIdx.x] = (float)lora_h[(size_t)btl * LR5 + f * 32 + threadIdx.x];
    __syncthreads();
    const float* Bf = B_lora + (size_t)f * 32 * CCH;
    size_t gbase = ((size_t)b * TT + t) * CCH;
    size_t lbase = (size_t)btl * CCH;
    #pragma unroll
    for (int q = 0; q < 4; ++q) {
        int c = threadIdx.x + q * 256;
        float xv = x[gbase + c];
        float xp = (t > 0) ? x[gbase + c - CCH] : 0.f;
        float miu = lambda_[f * CCH + c];
        #pragma unroll
        for (int ii = 0; ii < 32; ++ii)
            miu += lhs[ii] * Bf[ii * CCH + c];
        xx[lbase + c] = (bf16_t)(xv + (xp - xv) * miu);
    }
}

// ---------------- w = td_miu + td_h @ td_B  (f32 out; exp in scan) ----------------
__global__ __launch_bounds__(256) void wcomp_kernel(const bf16_t* __restrict__ td_h,
        const float* __restrict__ td_B, const float* __restrict__ td_miu,
        float* __restrict__ wout) {
    int btl = blockIdx.x;
    __shared__ float th[TDR];
    if (threadIdx.x < TDR) th[threadIdx.x] = (float)td_h[(size_t)btl * TDR + threadIdx.x];
    __syncthreads();
    #pragma unroll
    for (int q = 0; q < 4; ++q) {
        int c = threadIdx.x + q * 256;
        float acc = td_miu[c];
        #pragma unroll 8
        for (int jj = 0; jj < TDR; ++jj)
            acc += th[jj] * td_B[jj * CCH + c];
        wout[(size_t)btl * CCH + c] = acc;
    }
}

// ---------------- MFMA GEMM: out[m,n] = sum_k A[m,k]*Bw[n,k]; optional chunk->global C rows ----------------
#define BM 128
#define BN 128
#define BKK 64
#define LDSK 72   // BKK + 8 bf16 pad

enum { EPI_NONE = 0, EPI_SILU = 1, EPI_TANH = 2 };

template<int EPI, bool CMAP, typename OutT>
__global__ __launch_bounds__(256) void gemm_bt(const bf16_t* __restrict__ A,
        const bf16_t* __restrict__ Bw, OutT* __restrict__ Cm,
        int N, int K, int ldc, int cOff) {
    __shared__ __align__(16) bf16_t As[BM * LDSK];
    __shared__ __align__(16) bf16_t Bs[BN * LDSK];
    const int m0 = blockIdx.x * BM;
    const int n0 = blockIdx.y * BN;
    const int tid = threadIdx.x;
    const int w = tid >> 6, lane = tid & 63;
    const int wm = (w >> 1) * 64, wn = (w & 1) * 64;  // 2x2 waves, 64x64 each
    const int lrow = lane & 15;
    const int kq = (lane >> 4) * 8;
    f32x4 acc[4][4] = {};
    for (int k0 = 0; k0 < K; k0 += BKK) {
        __syncthreads();
        #pragma unroll
        for (int p = 0; p < 4; ++p) {
            int chunk = tid + p * 256;
            int row = chunk >> 3;
            int c8 = (chunk & 7) * 8;
            uint4 av = *(const uint4*)(A + (size_t)(m0 + row) * K + k0 + c8);
            *(uint4*)(&As[row * LDSK + c8]) = av;
            int n = n0 + row;
            uint4 bv = make_uint4(0u, 0u, 0u, 0u);
            if (n < N) bv = *(const uint4*)(Bw + (size_t)n * K + k0 + c8);
            *(uint4*)(&Bs[row * LDSK + c8]) = bv;
        }
        __syncthreads();
        #pragma unroll
        for (int kk = 0; kk < BKK; kk += 32) {
            bf16x8 af[4], bfr[4];
            #pragma unroll
            for (int mt = 0; mt < 4; ++mt)
                af[mt] = *(const bf16x8*)(&As[(wm + mt * 16 + lrow) * LDSK + kk + kq]);
            #pragma unroll
            for (int nt = 0; nt < 4; ++nt)
                bfr[nt] = *(const bf16x8*)(&Bs[(wn + nt * 16 + lrow) * LDSK + kk + kq]);
            #pragma unroll
            for (int mt = 0; mt < 4; ++mt)
                #pragma unroll
                for (int nt = 0; nt < 4; ++nt)
                    acc[mt][nt] = __builtin_amdgcn_mfma_f32_16x16x32_bf16(
                        af[mt], bfr[nt], acc[mt][nt], 0, 0, 0);
        }
    }
    // C/D layout: col = lane&15, row = (lane>>4)*4 + reg  [verified m89/m91]
    const int rbase = (lane >> 4) * 4;
    const int col = lane & 15;
    #pragma unroll
    for (int mt = 0; mt < 4; ++mt) {
        #pragma unroll
        for (int nt = 0; nt < 4; ++nt) {
            int n = n0 + wn + nt * 16 + col;
            if (n >= N) continue;
            #pragma unroll
            for (int rg = 0; rg < 4; ++rg) {
                int m = m0 + wm + mt * 16 + rbase + rg;
                size_t mg = CMAP ? ((size_t)(m >> TCLOG) * TT + cOff + (m & (TC - 1)))
                                 : (size_t)m;
                float vv = acc[mt][nt][rg];
                if (EPI == EPI_SILU) vv = vv / (1.f + expf(-vv));
                else if (EPI == EPI_TANH) vv = tanhf(vv);
                Cm[mg * ldc + n] = (OutT)vv;
            }
        }
    }
}

// ---------------- WKV6 pass 1: per-sub-chunk local scan from S=0 ----------------
// One wave per (bh, sc). Emits: y_local -> yloc; rr = r * P_excl IN-PLACE over r (ry);
// final local state -> Sloc (f32); inclusive decay product -> PL (f32).
__global__ __launch_bounds__(64) void wkv_local(bf16_t* ry,
        const bf16_t* __restrict__ k, const bf16_t* __restrict__ v,
        const float* __restrict__ w, const float* __restrict__ u,
        bf16_t* __restrict__ yloc, float* __restrict__ Sloc, float* __restrict__ PL) {
    const int bh = blockIdx.x, sc = blockIdx.y;
    const int b = bh >> 4, h = bh & 15;
    const int j = threadIdx.x;
    const size_t base = ((size_t)b * TC + sc * TSUB) * CCH + h * HSZ + j;
    float S[HSZ];
    #pragma unroll
    for (int i = 0; i < HSZ; ++i) S[i] = 0.f;
    __shared__ float4 lds[HSZ];
    const float uj = u[h * HSZ + j];
    float pex = 1.f;                            // exclusive cumprod of decay for channel j
    float rv = (float)ry[base], kv = (float)k[base], vv = (float)v[base];
    float wv = w[base];
    for (int t = 0; t < TSUB; ++t) {
        float dv = expf(-expf(wv));
        __syncthreads();
        lds[j] = make_float4(rv, kv, dv, rv * uj * kv);
        __syncthreads();
        float nrv = 0.f, nkv = 0.f, nvv = 0.f, nwv = 0.f;
        if (t + 1 < TSUB) {
            size_t ni = base + (size_t)(t + 1) * CCH;
            nrv = (float)ry[ni]; nkv = (float)k[ni]; nvv = (float)v[ni]; nwv = w[ni];
        }
        float yy = 0.f, aa = 0.f;
        #pragma unroll
        for (int i = 0; i < HSZ; ++i) {
            float4 p = lds[i];          // broadcast read, conflict-free
            yy += p.x * S[i];           // y uses pre-update local S
            aa += p.w;
            S[i] = p.z * S[i] + p.y * vv;
        }
        size_t oi = base + (size_t)t * CCH;
        yloc[oi] = (bf16_t)(yy + aa * vv);
        ry[oi] = (bf16_t)(rv * pex);    // rr_t = r_t * P_{t-1}, in-place over r
        pex *= dv;
        rv = nrv; kv = nkv; vv = nvv; wv = nwv;
    }
    const size_t so = ((size_t)bh * NSC + sc) * (HSZ * HSZ);
    #pragma unroll
    for (int i = 0; i < HSZ; ++i) Sloc[so + i * HSZ + j] = S[i];
    PL[((size_t)bh * NSC + sc) * HSZ + j] = pex;
}

// ---------------- WKV6 pass 2: serial state combine across sub-chunks ----------------
// S0st[bh][sc] = incoming state of sub-chunk sc; S_next = PL ⊙ S0 + Sloc.
__global__ __launch_bounds__(64) void wkv_combine(const float* __restrict__ Sloc,
        const float* __restrict__ PL, float* __restrict__ S0st,
        float* state, int cOuter) {
    const int bh = blockIdx.x;
    const int j = threadIdx.x;
    float* st = state + (size_t)bh * HSZ * HSZ;
    float S[HSZ];
    if (cOuter > 0) {
        #pragma unroll
        for (int i = 0; i < HSZ; ++i) S[i] = st[i * HSZ + j];
    } else {
        #pragma unroll
        for (int i = 0; i < HSZ; ++i) S[i] = 0.f;
    }
    __shared__ float pls[HSZ];
    for (int sc = 0; sc < NSC; ++sc) {
        const size_t so = ((size_t)bh * NSC + sc) * (HSZ * HSZ);
        pls[j] = PL[((size_t)bh * NSC + sc) * HSZ + j];
        __syncthreads();
        #pragma unroll
        for (int i = 0; i < HSZ; ++i) {
            S0st[so + i * HSZ + j] = S[i];
            S[i] = pls[i] * S[i] + Sloc[so + i * HSZ + j];
        }
        __syncthreads();
    }
    #pragma unroll
    for (int i = 0; i < HSZ; ++i) st[i * HSZ + j] = S[i];
}

// ---------------- WKV6 pass 3: y = y_local + rr @ S0  (parallel over sub-chunks) ----------------
__global__ __launch_bounds__(64) void wkv_correct(bf16_t* ry,
        const bf16_t* __restrict__ yloc, const float* __restrict__ S0st) {
    const int bh = blockIdx.x, sc = blockIdx.y;
    const int b = bh >> 4, h = bh & 15;
    const int j = threadIdx.x;
    const size_t base = ((size_t)b * TC + sc * TSUB) * CCH + h * HSZ + j;
    __shared__ bf16_t rrl[TSUB][HSZ];           // 8 KB
    for (int t = 0; t < TSUB; ++t)
        rrl[t][j] = ry[base + (size_t)t * CCH];  // stage ALL rr reads before any write
    __syncthreads();
    float s0[HSZ];
    const size_t so = ((size_t)bh * NSC + sc) * (HSZ * HSZ);
    #pragma unroll
    for (int i = 0; i < HSZ; ++i) s0[i] = S0st[so + i * HSZ + j];
    for (int t = 0; t < TSUB; ++t) {
        float acc = (float)yloc[base + (size_t)t * CCH];
        #pragma unroll
        for (int i = 0; i < HSZ; ++i)
            acc += (float)rrl[t][i] * s0[i];
        ry[base + (size_t)t * CCH] = (bf16_t)acc;  // final y, in-place
    }
}

// ---------------- GroupNorm(16 groups of 64) * g, in-place on y chunk ----------------
__global__ __launch_bounds__(256) void gn_kernel(bf16_t* yg,
        const float* __restrict__ g_glob, const float* __restrict__ gamma,
        const float* __restrict__ beta, int cOff) {
    int wave = threadIdx.x >> 6, lane = threadIdx.x & 63;
    int gid = blockIdx.x * 4 + wave;          // over MCH*HH
    int h = gid & (HH - 1);
    int ml = gid >> 4;                        // local token row
    int b = ml >> TCLOG, tau = ml & (TC - 1);
    size_t lidx = (size_t)ml * CCH + h * HSZ + lane;
    size_t gidx = ((size_t)b * TT + cOff + tau) * CCH + h * HSZ + lane;
    float val = (float)yg[lidx];
    float s = val, s2 = val * val;
    #pragma unroll
    for (int off = 32; off > 0; off >>= 1) {
        s  += __shfl_xor(s, off);
        s2 += __shfl_xor(s2, off);
    }
    float mean = s * (1.f / HSZ);
    float var  = fmaxf(s2 * (1.f / HSZ) - mean * mean, 0.f);
    float inv  = rsqrtf(var + 1e-5f * HH);
    float yn = (val - mean) * inv * gamma[h * HSZ + lane] + beta[h * HSZ + lane];
    yg[lidx] = (bf16_t)(yn * g_glob[gidx]);
}

extern "C" void kernel_launch(void* const* d_in, const int* in_sizes, int n_in,
                              void* d_out, int out_size, void* d_ws, size_t ws_size,
                              hipStream_t stream) {
    const float* x       = (const float*)d_in[0];
    const float* miu_x   = (const float*)d_in[1];
    const float* lambda_ = (const float*)d_in[2];
    const float* A_lora  = (const float*)d_in[3];
    const float* B_lora  = (const float*)d_in[4];
    const float* td_miu  = (const float*)d_in[5];
    const float* td_A    = (const float*)d_in[6];
    const float* td_B    = (const float*)d_in[7];
    const float* u       = (const float*)d_in[8];
    const float* Wr      = (const float*)d_in[9];
    const float* Wk      = (const float*)d_in[10];
    const float* Wv      = (const float*)d_in[11];
    const float* Wg      = (const float*)d_in[12];
    const float* Wo      = (const float*)d_in[13];
    const float* gamma   = (const float*)d_in[14];
    const float* beta    = (const float*)d_in[15];
    float* out = (float*)d_out;

    // ---- workspace carve-up: ~103 MiB total ----
    char* ws = (char*)d_ws;
    size_t off = 0;
    auto alloc = [&](size_t bytes) {
        char* p = ws + off;
        off += (bytes + 255) & ~(size_t)255;
        return (void*)p;
    };
    const size_t MCC = (size_t)MCH * CCH;               // 4M elems per chunk buffer
    bf16_t* xxc  = (bf16_t*)alloc(MCC * 2);             // xm / xx scratch (reused)
    bf16_t* kc   = (bf16_t*)alloc(MCC * 2);
    bf16_t* vc   = (bf16_t*)alloc(MCC * 2);
    float*  wc   = (float*)alloc(MCC * 4);              // f32: decay-compounding sensitivity
    bf16_t* ryc  = (bf16_t*)alloc(MCC * 2);             // r -> rr -> y -> yn*g
    bf16_t* yc   = (bf16_t*)alloc(MCC * 2);             // y_local
    bf16_t* lhc  = (bf16_t*)alloc((size_t)MCH * LR5 * 2);
    bf16_t* tdhc = (bf16_t*)alloc((size_t)MCH * TDR * 2);
    bf16_t* At   = (bf16_t*)alloc((size_t)LR5 * CCH * 2);
    bf16_t* tdAt = (bf16_t*)alloc((size_t)TDR * CCH * 2);
    bf16_t* Wb[5];
    for (int i = 0; i < 5; ++i) Wb[i] = (bf16_t*)alloc((size_t)CCH * CCH * 2);
    float*  state = (float*)alloc((size_t)BBHH * HSZ * HSZ * 4);            // 2 MB
    float*  Sloc  = (float*)alloc((size_t)BBHH * NSC * HSZ * HSZ * 4);      // 16 MB
    float*  S0st  = (float*)alloc((size_t)BBHH * NSC * HSZ * HSZ * 4);      // 16 MB
    float*  PL    = (float*)alloc((size_t)BBHH * NSC * HSZ * 4);            // 256 KB
    (void)ws_size; (void)in_sizes; (void)n_in; (void)out_size;
    bf16_t* Wrb = Wb[0]; bf16_t* Wkb = Wb[1]; bf16_t* Wvb = Wb[2];
    bf16_t* Wgb = Wb[3]; bf16_t* Wob = Wb[4];

    // weight prep: Wx are already [n,k] (reference does x @ W.T) -> convert only
    const int WN = CCH * CCH;
    f2b_kernel<<<(WN + 255) / 256, 256, 0, stream>>>(Wr, Wrb, WN);
    f2b_kernel<<<(WN + 255) / 256, 256, 0, stream>>>(Wk, Wkb, WN);
    f2b_kernel<<<(WN + 255) / 256, 256, 0, stream>>>(Wv, Wvb, WN);
    f2b_kernel<<<(WN + 255) / 256, 256, 0, stream>>>(Wg, Wgb, WN);
    f2b_kernel<<<(WN + 255) / 256, 256, 0, stream>>>(Wo, Wob, WN);
    transb_kernel<<<(CCH * LR5 + 255) / 256, 256, 0, stream>>>(A_lora, At, CCH, LR5);
    transb_kernel<<<(CCH * TDR + 255) / 256, 256, 0, stream>>>(td_A, tdAt, CCH, TDR);

    for (int c = 0; c < NCHUNK; ++c) {
        const int cOff = c * TC;
        // lora_h for this chunk
        xm_kernel<<<MCC / 256, 256, 0, stream>>>(x, miu_x, xxc, cOff);
        gemm_bt<EPI_TANH, false, bf16_t><<<dim3(MCH / BM, 2), 256, 0, stream>>>(
            xxc, At, lhc, LR5, CCH, LR5, 0);
        // w branch
        xx_kernel<<<MCH, 256, 0, stream>>>(x, lambda_, lhc, B_lora, 0, xxc, cOff);
        gemm_bt<EPI_TANH, false, bf16_t><<<dim3(MCH / BM, 1), 256, 0, stream>>>(
            xxc, tdAt, tdhc, TDR, CCH, TDR, 0);
        wcomp_kernel<<<MCH, 256, 0, stream>>>(tdhc, td_B, td_miu, wc);
        // k, v branches
        xx_kernel<<<MCH, 256, 0, stream>>>(x, lambda_, lhc, B_lora, 1, xxc, cOff);
        gemm_bt<EPI_NONE, false, bf16_t><<<dim3(MCH / BM, CCH / BN), 256, 0, stream>>>(
            xxc, Wkb, kc, CCH, CCH, CCH, 0);
        xx_kernel<<<MCH, 256, 0, stream>>>(x, lambda_, lhc, B_lora, 2, xxc, cOff);
        gemm_bt<EPI_NONE, false, bf16_t><<<dim3(MCH / BM, CCH / BN), 256, 0, stream>>>(
            xxc, Wvb, vc, CCH, CCH, CCH, 0);
        // g branch -> parked f32 in d_out (global rows of this chunk) until GroupNorm
        xx_kernel<<<MCH, 256, 0, stream>>>(x, lambda_, lhc, B_lora, 4, xxc, cOff);
        gemm_bt<EPI_SILU, true, float><<<dim3(MCH / BM, CCH / BN), 256, 0, stream>>>(
            xxc, Wgb, out, CCH, CCH, CCH, cOff);
        // r branch
        xx_kernel<<<MCH, 256, 0, stream>>>(x, lambda_, lhc, B_lora, 3, xxc, cOff);
        gemm_bt<EPI_NONE, false, bf16_t><<<dim3(MCH / BM, CCH / BN), 256, 0, stream>>>(
            xxc, Wrb, ryc, CCH, CCH, CCH, 0);
        // two-level scan: parallel local scans, serial combine, parallel correction
        wkv_local<<<dim3(BBHH, NSC), 64, 0, stream>>>(ryc, kc, vc, wc, u, yc, Sloc, PL);
        wkv_combine<<<BBHH, 64, 0, stream>>>(Sloc, PL, S0st, state, c);
        wkv_correct<<<dim3(BBHH, NSC), 64, 0, stream>>>(ryc, yc, S0st);
        // groupnorm * g (reads g rows from d_out, in-place on y), then Wo projection (f32 out)
        gn_kernel<<<(MCH * HH) / 4, 256, 0, stream>>>(ryc, out, gamma, beta, cOff);
        gemm_bt<EPI_NONE, true, float><<<dim3(MCH / BM, CCH / BN), 256, 0, stream>>>(
            ryc, Wob, out, CCH, CCH, CCH, cOff);
    }
}

// Round 7
// 2272.405 us; speedup vs baseline: 2.3124x; 1.2260x over previous
//
#include <hip/hip_runtime.h>
#include <hip/hip_bf16.h>
#include <cstdint>

typedef __bf16 bf16_t;
typedef __bf16 bf16x8 __attribute__((ext_vector_type(8)));
typedef float f32x4 __attribute__((ext_vector_type(4)));

#define BB 8
#define TT 2048
#define TC 512             // outer chunk length (4 chunks)
#define TCLOG 9
#define NCHUNK 4
#define MCH (BB*TC)        // 4096 local rows per chunk
#define CCH 1024
#define HH 16
#define HSZ 64
#define LR5 160            // 5 * LORA_R
#define TDR 64
#define TSUB 64            // scan sub-chunk length
#define NSC (TC/TSUB)      // 8 sub-chunks per outer chunk
#define BBHH (BB*HH)       // 128
#define LDP 72             // LDS tile pitch (64 + 8, b128-aligned)

// ---------------- f32 -> bf16 convert ----------------
__global__ __launch_bounds__(256) void f2b_kernel(const float* __restrict__ in,
        bf16_t* __restrict__ out, int n) {
    int i = blockIdx.x * 256 + threadIdx.x;
    if (i < n) out[i] = (bf16_t)in[i];
}

// ---------------- transpose + convert: (R,Cc) f32 -> (Cc,R) bf16 ----------------
__global__ __launch_bounds__(256) void transb_kernel(const float* __restrict__ in,
        bf16_t* __restrict__ out, int R, int Cc) {
    int i = blockIdx.x * 256 + threadIdx.x;
    if (i >= R * Cc) return;
    int r = i / Cc, c = i - r * Cc;
    out[c * R + r] = (bf16_t)in[i];
}

// ---------------- xm = x + (x_prev - x) * miu_x   (f32 in, bf16 out, chunk rows) ----------------
__global__ __launch_bounds__(256) void xm_kernel(const float* __restrict__ x,
        const float* __restrict__ miu_x, bf16_t* __restrict__ xm, int cOff) {
    long long i = (long long)blockIdx.x * 256 + threadIdx.x;   // over MCH*CCH
    int ch = (int)(i & (CCH - 1));
    int btl = (int)(i >> 10);                 // local row in [0, MCH)
    int b = btl >> TCLOG, tau = btl & (TC - 1);
    int t = cOff + tau;
    size_t gi = ((size_t)b * TT + t) * CCH + ch;
    float xv = x[gi];
    float xp = (t > 0) ? x[gi - CCH] : 0.f;
    xm[i] = (bf16_t)(xv + (xp - xv) * miu_x[ch]);
}

// ---------------- xx_f = x + dxa * (lambda_f + lora_h_f @ B_lora_f)  (f32 in, bf16 out) ----------------
__global__ __launch_bounds__(256) void xx_kernel(const float* __restrict__ x,
        const float* __restrict__ lambda_, const bf16_t* __restrict__ lora_h,
        const float* __restrict__ B_lora, int f, bf16_t* __restrict__ xx, int cOff) {
    int btl = blockIdx.x;                     // local token row
    int b = btl >> TCLOG, tau = btl & (TC - 1);
    int t = cOff + tau;
    __shared__ float lhs[32];
    if (threadIdx.x < 32) lhs[threadIdx.x] = (float)lora_h[(size_t)btl * LR5 + f * 32 + threadIdx.x];
    __syncthreads();
    const float* Bf = B_lora + (size_t)f * 32 * CCH;
    size_t gbase = ((size_t)b * TT + t) * CCH;
    size_t lbase = (size_t)btl * CCH;
    #pragma unroll
    for (int q = 0; q < 4; ++q) {
        int c = threadIdx.x + q * 256;
        float xv = x[gbase + c];
        float xp = (t > 0) ? x[gbase + c - CCH] : 0.f;
        float miu = lambda_[f * CCH + c];
        #pragma unroll
        for (int ii = 0; ii < 32; ++ii)
            miu += lhs[ii] * Bf[ii * CCH + c];
        xx[lbase + c] = (bf16_t)(xv + (xp - xv) * miu);
    }
}

// ---------------- w = td_miu + td_h @ td_B  (f32 out; exp in scan) ----------------
__global__ __launch_bounds__(256) void wcomp_kernel(const bf16_t* __restrict__ td_h,
        const float* __restrict__ td_B, const float* __restrict__ td_miu,
        float* __restrict__ wout) {
    int btl = blockIdx.x;
    __shared__ float th[TDR];
    if (threadIdx.x < TDR) th[threadIdx.x] = (float)td_h[(size_t)btl * TDR + threadIdx.x];
    __syncthreads();
    #pragma unroll
    for (int q = 0; q < 4; ++q) {
        int c = threadIdx.x + q * 256;
        float acc = td_miu[c];
        #pragma unroll 8
        for (int jj = 0; jj < TDR; ++jj)
            acc += th[jj] * td_B[jj * CCH + c];
        wout[(size_t)btl * CCH + c] = acc;
    }
}

// ---------------- MFMA GEMM: out[m,n] = sum_k A[m,k]*Bw[n,k]; optional chunk->global C rows ----------------
#define BM 128
#define BN 128
#define BKK 64
#define LDSK 72   // BKK + 8 bf16 pad

enum { EPI_NONE = 0, EPI_SILU = 1, EPI_TANH = 2 };

template<int EPI, bool CMAP, typename OutT>
__global__ __launch_bounds__(256) void gemm_bt(const bf16_t* __restrict__ A,
        const bf16_t* __restrict__ Bw, OutT* __restrict__ Cm,
        int N, int K, int ldc, int cOff) {
    __shared__ __align__(16) bf16_t As[BM * LDSK];
    __shared__ __align__(16) bf16_t Bs[BN * LDSK];
    const int m0 = blockIdx.x * BM;
    const int n0 = blockIdx.y * BN;
    const int tid = threadIdx.x;
    const int w = tid >> 6, lane = tid & 63;
    const int wm = (w >> 1) * 64, wn = (w & 1) * 64;  // 2x2 waves, 64x64 each
    const int lrow = lane & 15;
    const int kq = (lane >> 4) * 8;
    f32x4 acc[4][4] = {};
    for (int k0 = 0; k0 < K; k0 += BKK) {
        __syncthreads();
        #pragma unroll
        for (int p = 0; p < 4; ++p) {
            int chunk = tid + p * 256;
            int row = chunk >> 3;
            int c8 = (chunk & 7) * 8;
            uint4 av = *(const uint4*)(A + (size_t)(m0 + row) * K + k0 + c8);
            *(uint4*)(&As[row * LDSK + c8]) = av;
            int n = n0 + row;
            uint4 bv = make_uint4(0u, 0u, 0u, 0u);
            if (n < N) bv = *(const uint4*)(Bw + (size_t)n * K + k0 + c8);
            *(uint4*)(&Bs[row * LDSK + c8]) = bv;
        }
        __syncthreads();
        #pragma unroll
        for (int kk = 0; kk < BKK; kk += 32) {
            bf16x8 af[4], bfr[4];
            #pragma unroll
            for (int mt = 0; mt < 4; ++mt)
                af[mt] = *(const bf16x8*)(&As[(wm + mt * 16 + lrow) * LDSK + kk + kq]);
            #pragma unroll
            for (int nt = 0; nt < 4; ++nt)
                bfr[nt] = *(const bf16x8*)(&Bs[(wn + nt * 16 + lrow) * LDSK + kk + kq]);
            #pragma unroll
            for (int mt = 0; mt < 4; ++mt)
                #pragma unroll
                for (int nt = 0; nt < 4; ++nt)
                    acc[mt][nt] = __builtin_amdgcn_mfma_f32_16x16x32_bf16(
                        af[mt], bfr[nt], acc[mt][nt], 0, 0, 0);
        }
    }
    // C/D layout: col = lane&15, row = (lane>>4)*4 + reg  [verified m89/m91]
    const int rbase = (lane >> 4) * 4;
    const int col = lane & 15;
    #pragma unroll
    for (int mt = 0; mt < 4; ++mt) {
        #pragma unroll
        for (int nt = 0; nt < 4; ++nt) {
            int n = n0 + wn + nt * 16 + col;
            if (n >= N) continue;
            #pragma unroll
            for (int rg = 0; rg < 4; ++rg) {
                int m = m0 + wm + mt * 16 + rbase + rg;
                size_t mg = CMAP ? ((size_t)(m >> TCLOG) * TT + cOff + (m & (TC - 1)))
                                 : (size_t)m;
                float vv = acc[mt][nt][rg];
                if (EPI == EPI_SILU) vv = vv / (1.f + expf(-vv));
                else if (EPI == EPI_TANH) vv = tanhf(vv);
                Cm[mg * ldc + n] = (OutT)vv;
            }
        }
    }
}

// ---------------- WKV6 pass 1: decay cumprods + scaled operand tiles (register-only) ----------------
// rr_t = r_t * Pex_t  -> rrT tile [t][j];  kt_s = k_s / Pinc_s -> ktT tile [s][j];
// b_t = sum_j r u k (diag bonus) -> bvec;  PL = Pinc_{L-1}.
__global__ __launch_bounds__(64) void wkv_prep(const bf16_t* __restrict__ ry,
        const bf16_t* __restrict__ k, const float* __restrict__ w,
        const float* __restrict__ u, bf16_t* __restrict__ rrT,
        bf16_t* __restrict__ ktT, float* __restrict__ PL, float* __restrict__ bvec) {
    const int bh = blockIdx.x, sc = blockIdx.y;
    const int b = bh >> 4, h = bh & 15;
    const int j = threadIdx.x;
    const size_t base = ((size_t)b * TC + sc * TSUB) * CCH + h * HSZ + j;
    const size_t tile = ((size_t)bh * NSC + sc) * (TSUB * HSZ);
    const size_t vb = ((size_t)bh * NSC + sc) * TSUB;
    const float uj = u[h * HSZ + j];
    float pex = 1.f;
    for (int t = 0; t < TSUB; ++t) {
        size_t idx = base + (size_t)t * CCH;
        float rv = (float)ry[idx], kv = (float)k[idx], wv = w[idx];
        float d = expf(-expf(wv));
        rrT[tile + t * HSZ + j] = (bf16_t)(rv * pex);
        float pinc = pex * d;
        ktT[tile + t * HSZ + j] = (bf16_t)(kv / pinc);   // |kt| <= ~3e11, bf16-safe
        float bu = rv * uj * kv;
        #pragma unroll
        for (int off = 1; off < 64; off <<= 1) bu += __shfl_xor(bu, off);
        if (j == 0) bvec[vb + t] = bu;
        pex = pinc;
    }
    PL[vb * 0 + ((size_t)bh * NSC + sc) * HSZ + j] = pex;
}

// ---------------- WKV6 pass 2a: Sloc[i][j] = sum_s (kt[s][i]*PL[i]) * v[s][j]  via MFMA ----------------
__global__ __launch_bounds__(64) void wkv_sgemm(const bf16_t* __restrict__ ktT,
        const bf16_t* __restrict__ v, const float* __restrict__ PL,
        float* __restrict__ Sloc) {
    const int bh = blockIdx.x, sc = blockIdx.y;
    const int b = bh >> 4, h = bh & 15;
    const int j = threadIdx.x;
    const size_t tile = ((size_t)bh * NSC + sc) * (TSUB * HSZ);
    const size_t basev = ((size_t)b * TC + sc * TSUB) * CCH + h * HSZ + j;
    __shared__ __align__(16) bf16_t ksT[HSZ * LDP];   // [i][s] = kt[s][i]*PL[i]
    __shared__ __align__(16) bf16_t vtT[HSZ * LDP];   // [j][s] = v[s][j]
    const float plj = PL[((size_t)bh * NSC + sc) * HSZ + j];
    for (int s = 0; s < TSUB; ++s) {
        float kt = (float)ktT[tile + s * HSZ + j];
        ksT[j * LDP + s] = (bf16_t)(kt * plj);
        vtT[j * LDP + s] = v[basev + (size_t)s * CCH];
    }
    __syncthreads();
    const int lane = j;
    const int lrow = lane & 15, kq = (lane >> 4) * 8;
    f32x4 acc[4][4] = {};
    #pragma unroll
    for (int kk = 0; kk < TSUB; kk += 32) {
        bf16x8 af[4], bfr[4];
        #pragma unroll
        for (int mt = 0; mt < 4; ++mt)
            af[mt] = *(const bf16x8*)(&ksT[(mt * 16 + lrow) * LDP + kk + kq]);
        #pragma unroll
        for (int nt = 0; nt < 4; ++nt)
            bfr[nt] = *(const bf16x8*)(&vtT[(nt * 16 + lrow) * LDP + kk + kq]);
        #pragma unroll
        for (int mt = 0; mt < 4; ++mt)
            #pragma unroll
            for (int nt = 0; nt < 4; ++nt)
                acc[mt][nt] = __builtin_amdgcn_mfma_f32_16x16x32_bf16(
                    af[mt], bfr[nt], acc[mt][nt], 0, 0, 0);
    }
    const int rbase = (lane >> 4) * 4, col = lane & 15;
    #pragma unroll
    for (int mt = 0; mt < 4; ++mt)
        #pragma unroll
        for (int nt = 0; nt < 4; ++nt)
            #pragma unroll
            for (int rg = 0; rg < 4; ++rg) {
                int i = mt * 16 + rbase + rg, n = nt * 16 + col;
                Sloc[tile + i * HSZ + n] = acc[mt][nt][rg];
            }
}

// ---------------- WKV6 pass 2b: serial state combine across sub-chunks (unchanged) ----------------
__global__ __launch_bounds__(64) void wkv_combine(const float* __restrict__ Sloc,
        const float* __restrict__ PL, float* __restrict__ S0st,
        float* state, int cOuter) {
    const int bh = blockIdx.x;
    const int j = threadIdx.x;
    float* st = state + (size_t)bh * HSZ * HSZ;
    float S[HSZ];
    if (cOuter > 0) {
        #pragma unroll
        for (int i = 0; i < HSZ; ++i) S[i] = st[i * HSZ + j];
    } else {
        #pragma unroll
        for (int i = 0; i < HSZ; ++i) S[i] = 0.f;
    }
    __shared__ float pls[HSZ];
    for (int sc = 0; sc < NSC; ++sc) {
        const size_t so = ((size_t)bh * NSC + sc) * (HSZ * HSZ);
        pls[j] = PL[((size_t)bh * NSC + sc) * HSZ + j];
        __syncthreads();
        #pragma unroll
        for (int i = 0; i < HSZ; ++i) {
            S0st[so + i * HSZ + j] = S[i];
            S[i] = pls[i] * S[i] + Sloc[so + i * HSZ + j];
        }
        __syncthreads();
    }
    #pragma unroll
    for (int i = 0; i < HSZ; ++i) st[i * HSZ + j] = S[i];
}

// ---------------- WKV6 pass 3: Y = (mask(RR@KTt) + diag(b)) @ V + RR @ S0  via MFMA ----------------
__global__ __launch_bounds__(64) void wkv_y(bf16_t* __restrict__ ry,
        const bf16_t* __restrict__ rrT, const bf16_t* __restrict__ ktT,
        const bf16_t* __restrict__ v, const float* __restrict__ S0st,
        const float* __restrict__ bvec) {
    const int bh = blockIdx.x, sc = blockIdx.y;
    const int b = bh >> 4, h = bh & 15;
    const int j = threadIdx.x;
    const size_t tile = ((size_t)bh * NSC + sc) * (TSUB * HSZ);
    const size_t basev = ((size_t)b * TC + sc * TSUB) * CCH + h * HSZ;
    __shared__ __align__(16) bf16_t vtT[HSZ * LDP];   // [j][s] = v[s][j]
    __shared__ __align__(16) bf16_t s0T[HSZ * LDP];   // [j][i] = S0[i][j]
    __shared__ __align__(16) bf16_t am[TSUB * LDP];   // masked A [t][s]
    __shared__ float bl[TSUB];
    for (int s = 0; s < TSUB; ++s)
        vtT[j * LDP + s] = v[basev + (size_t)s * CCH + j];
    for (int i = 0; i < HSZ; ++i)
        s0T[j * LDP + i] = (bf16_t)S0st[tile + i * HSZ + j];
    bl[j] = bvec[((size_t)bh * NSC + sc) * TSUB + j];
    __syncthreads();
    const bf16_t* rrt = rrT + tile;
    const bf16_t* ktt = ktT + tile;
    const int lane = j;
    const int lrow = lane & 15, kq = (lane >> 4) * 8;
    const int rbase = (lane >> 4) * 4, col = lane & 15;
    // phase 1: A = RR @ KTt^T  (K = channel)
    f32x4 acc[4][4] = {};
    #pragma unroll
    for (int kk = 0; kk < HSZ; kk += 32) {
        bf16x8 af[4], bfr[4];
        #pragma unroll
        for (int mt = 0; mt < 4; ++mt)
            af[mt] = *(const bf16x8*)(rrt + (mt * 16 + lrow) * HSZ + kk + kq);
        #pragma unroll
        for (int nt = 0; nt < 4; ++nt)
            bfr[nt] = *(const bf16x8*)(ktt + (nt * 16 + lrow) * HSZ + kk + kq);
        #pragma unroll
        for (int mt = 0; mt < 4; ++mt)
            #pragma unroll
            for (int nt = 0; nt < 4; ++nt)
                acc[mt][nt] = __builtin_amdgcn_mfma_f32_16x16x32_bf16(
                    af[mt], bfr[nt], acc[mt][nt], 0, 0, 0);
    }
    // mask strict-lower, diag = b_t, upper = 0; C-layout -> LDS (A-layout for next GEMM)
    #pragma unroll
    for (int mt = 0; mt < 4; ++mt)
        #pragma unroll
        for (int nt = 0; nt < 4; ++nt)
            #pragma unroll
            for (int rg = 0; rg < 4; ++rg) {
                int t = mt * 16 + rbase + rg, s = nt * 16 + col;
                float aval = (s < t) ? acc[mt][nt][rg] : ((s == t) ? bl[t] : 0.f);
                am[t * LDP + s] = (bf16_t)aval;
            }
    __syncthreads();
    // phase 2: Y = A @ V  (K = s)  +  RR @ S0 (K = i)
    f32x4 yac[4][4] = {};
    #pragma unroll
    for (int kk = 0; kk < TSUB; kk += 32) {
        bf16x8 af[4], bfr[4];
        #pragma unroll
        for (int mt = 0; mt < 4; ++mt)
            af[mt] = *(const bf16x8*)(&am[(mt * 16 + lrow) * LDP + kk + kq]);
        #pragma unroll
        for (int nt = 0; nt < 4; ++nt)
            bfr[nt] = *(const bf16x8*)(&vtT[(nt * 16 + lrow) * LDP + kk + kq]);
        #pragma unroll
        for (int mt = 0; mt < 4; ++mt)
            #pragma unroll
            for (int nt = 0; nt < 4; ++nt)
                yac[mt][nt] = __builtin_amdgcn_mfma_f32_16x16x32_bf16(
                    af[mt], bfr[nt], yac[mt][nt], 0, 0, 0);
    }
    #pragma unroll
    for (int kk = 0; kk < HSZ; kk += 32) {
        bf16x8 af[4], bfr[4];
        #pragma unroll
        for (int mt = 0; mt < 4; ++mt)
            af[mt] = *(const bf16x8*)(rrt + (mt * 16 + lrow) * HSZ + kk + kq);
        #pragma unroll
        for (int nt = 0; nt < 4; ++nt)
            bfr[nt] = *(const bf16x8*)(&s0T[(nt * 16 + lrow) * LDP + kk + kq]);
        #pragma unroll
        for (int mt = 0; mt < 4; ++mt)
            #pragma unroll
            for (int nt = 0; nt < 4; ++nt)
                yac[mt][nt] = __builtin_amdgcn_mfma_f32_16x16x32_bf16(
                    af[mt], bfr[nt], yac[mt][nt], 0, 0, 0);
    }
    // write final y (in-place over r buffer)
    #pragma unroll
    for (int mt = 0; mt < 4; ++mt)
        #pragma unroll
        for (int nt = 0; nt < 4; ++nt)
            #pragma unroll
            for (int rg = 0; rg < 4; ++rg) {
                int t = mt * 16 + rbase + rg, jc = nt * 16 + col;
                ry[basev + (size_t)t * CCH + jc] = (bf16_t)yac[mt][nt][rg];
            }
}

// ---------------- GroupNorm(16 groups of 64) * g, in-place on y chunk ----------------
__global__ __launch_bounds__(256) void gn_kernel(bf16_t* yg,
        const float* __restrict__ g_glob, const float* __restrict__ gamma,
        const float* __restrict__ beta, int cOff) {
    int wave = threadIdx.x >> 6, lane = threadIdx.x & 63;
    int gid = blockIdx.x * 4 + wave;          // over MCH*HH
    int h = gid & (HH - 1);
    int ml = gid >> 4;                        // local token row
    int b = ml >> TCLOG, tau = ml & (TC - 1);
    size_t lidx = (size_t)ml * CCH + h * HSZ + lane;
    size_t gidx = ((size_t)b * TT + cOff + tau) * CCH + h * HSZ + lane;
    float val = (float)yg[lidx];
    float s = val, s2 = val * val;
    #pragma unroll
    for (int off = 32; off > 0; off >>= 1) {
        s  += __shfl_xor(s, off);
        s2 += __shfl_xor(s2, off);
    }
    float mean = s * (1.f / HSZ);
    float var  = fmaxf(s2 * (1.f / HSZ) - mean * mean, 0.f);
    float inv  = rsqrtf(var + 1e-5f * HH);
    float yn = (val - mean) * inv * gamma[h * HSZ + lane] + beta[h * HSZ + lane];
    yg[lidx] = (bf16_t)(yn * g_glob[gidx]);
}

extern "C" void kernel_launch(void* const* d_in, const int* in_sizes, int n_in,
                              void* d_out, int out_size, void* d_ws, size_t ws_size,
                              hipStream_t stream) {
    const float* x       = (const float*)d_in[0];
    const float* miu_x   = (const float*)d_in[1];
    const float* lambda_ = (const float*)d_in[2];
    const float* A_lora  = (const float*)d_in[3];
    const float* B_lora  = (const float*)d_in[4];
    const float* td_miu  = (const float*)d_in[5];
    const float* td_A    = (const float*)d_in[6];
    const float* td_B    = (const float*)d_in[7];
    const float* u       = (const float*)d_in[8];
    const float* Wr      = (const float*)d_in[9];
    const float* Wk      = (const float*)d_in[10];
    const float* Wv      = (const float*)d_in[11];
    const float* Wg      = (const float*)d_in[12];
    const float* Wo      = (const float*)d_in[13];
    const float* gamma   = (const float*)d_in[14];
    const float* beta    = (const float*)d_in[15];
    float* out = (float*)d_out;

    // ---- workspace carve-up: ~119 MiB total ----
    char* ws = (char*)d_ws;
    size_t off = 0;
    auto alloc = [&](size_t bytes) {
        char* p = ws + off;
        off += (bytes + 255) & ~(size_t)255;
        return (void*)p;
    };
    const size_t MCC = (size_t)MCH * CCH;               // 4M elems per chunk buffer
    bf16_t* xxc  = (bf16_t*)alloc(MCC * 2);             // xm / xx scratch (reused)
    bf16_t* kc   = (bf16_t*)alloc(MCC * 2);
    bf16_t* vc   = (bf16_t*)alloc(MCC * 2);
    float*  wc   = (float*)alloc(MCC * 4);              // f32: decay-compounding sensitivity
    bf16_t* ryc  = (bf16_t*)alloc(MCC * 2);             // r -> y -> yn*g
    bf16_t* rrT  = (bf16_t*)alloc(MCC * 2);             // rr tiles [bh][sc][t][j]
    bf16_t* ktT  = (bf16_t*)alloc(MCC * 2);             // kt tiles [bh][sc][s][j]
    bf16_t* lhc  = (bf16_t*)alloc((size_t)MCH * LR5 * 2);
    bf16_t* tdhc = (bf16_t*)alloc((size_t)MCH * TDR * 2);
    bf16_t* At   = (bf16_t*)alloc((size_t)LR5 * CCH * 2);
    bf16_t* tdAt = (bf16_t*)alloc((size_t)TDR * CCH * 2);
    bf16_t* Wb[5];
    for (int i = 0; i < 5; ++i) Wb[i] = (bf16_t*)alloc((size_t)CCH * CCH * 2);
    float*  state = (float*)alloc((size_t)BBHH * HSZ * HSZ * 4);            // 2 MB
    float*  Sloc  = (float*)alloc((size_t)BBHH * NSC * HSZ * HSZ * 4);      // 16 MB
    float*  S0st  = (float*)alloc((size_t)BBHH * NSC * HSZ * HSZ * 4);      // 16 MB
    float*  PL    = (float*)alloc((size_t)BBHH * NSC * HSZ * 4);            // 256 KB
    float*  bvec  = (float*)alloc((size_t)BBHH * NSC * TSUB * 4);           // 256 KB
    (void)ws_size; (void)in_sizes; (void)n_in; (void)out_size;
    bf16_t* Wrb = Wb[0]; bf16_t* Wkb = Wb[1]; bf16_t* Wvb = Wb[2];
    bf16_t* Wgb = Wb[3]; bf16_t* Wob = Wb[4];

    // weight prep: Wx are already [n,k] (reference does x @ W.T) -> convert only
    const int WN = CCH * CCH;
    f2b_kernel<<<(WN + 255) / 256, 256, 0, stream>>>(Wr, Wrb, WN);
    f2b_kernel<<<(WN + 255) / 256, 256, 0, stream>>>(Wk, Wkb, WN);
    f2b_kernel<<<(WN + 255) / 256, 256, 0, stream>>>(Wv, Wvb, WN);
    f2b_kernel<<<(WN + 255) / 256, 256, 0, stream>>>(Wg, Wgb, WN);
    f2b_kernel<<<(WN + 255) / 256, 256, 0, stream>>>(Wo, Wob, WN);
    transb_kernel<<<(CCH * LR5 + 255) / 256, 256, 0, stream>>>(A_lora, At, CCH, LR5);
    transb_kernel<<<(CCH * TDR + 255) / 256, 256, 0, stream>>>(td_A, tdAt, CCH, TDR);

    for (int c = 0; c < NCHUNK; ++c) {
        const int cOff = c * TC;
        // lora_h for this chunk
        xm_kernel<<<MCC / 256, 256, 0, stream>>>(x, miu_x, xxc, cOff);
        gemm_bt<EPI_TANH, false, bf16_t><<<dim3(MCH / BM, 2), 256, 0, stream>>>(
            xxc, At, lhc, LR5, CCH, LR5, 0);
        // w branch
        xx_kernel<<<MCH, 256, 0, stream>>>(x, lambda_, lhc, B_lora, 0, xxc, cOff);
        gemm_bt<EPI_TANH, false, bf16_t><<<dim3(MCH / BM, 1), 256, 0, stream>>>(
            xxc, tdAt, tdhc, TDR, CCH, TDR, 0);
        wcomp_kernel<<<MCH, 256, 0, stream>>>(tdhc, td_B, td_miu, wc);
        // k, v branches
        xx_kernel<<<MCH, 256, 0, stream>>>(x, lambda_, lhc, B_lora, 1, xxc, cOff);
        gemm_bt<EPI_NONE, false, bf16_t><<<dim3(MCH / BM, CCH / BN), 256, 0, stream>>>(
            xxc, Wkb, kc, CCH, CCH, CCH, 0);
        xx_kernel<<<MCH, 256, 0, stream>>>(x, lambda_, lhc, B_lora, 2, xxc, cOff);
        gemm_bt<EPI_NONE, false, bf16_t><<<dim3(MCH / BM, CCH / BN), 256, 0, stream>>>(
            xxc, Wvb, vc, CCH, CCH, CCH, 0);
        // g branch -> parked f32 in d_out (global rows of this chunk) until GroupNorm
        xx_kernel<<<MCH, 256, 0, stream>>>(x, lambda_, lhc, B_lora, 4, xxc, cOff);
        gemm_bt<EPI_SILU, true, float><<<dim3(MCH / BM, CCH / BN), 256, 0, stream>>>(
            xxc, Wgb, out, CCH, CCH, CCH, cOff);
        // r branch
        xx_kernel<<<MCH, 256, 0, stream>>>(x, lambda_, lhc, B_lora, 3, xxc, cOff);
        gemm_bt<EPI_NONE, false, bf16_t><<<dim3(MCH / BM, CCH / BN), 256, 0, stream>>>(
            xxc, Wrb, ryc, CCH, CCH, CCH, 0);
        // chunked-GEMM scan: prep -> state GEMM -> serial combine -> Y GEMM
        wkv_prep<<<dim3(BBHH, NSC), 64, 0, stream>>>(ryc, kc, wc, u, rrT, ktT, PL, bvec);
        wkv_sgemm<<<dim3(BBHH, NSC), 64, 0, stream>>>(ktT, vc, PL, Sloc);
        wkv_combine<<<BBHH, 64, 0, stream>>>(Sloc, PL, S0st, state, c);
        wkv_y<<<dim3(BBHH, NSC), 64, 0, stream>>>(ryc, rrT, ktT, vc, S0st, bvec);
        // groupnorm * g (reads g rows from d_out, in-place on y), then Wo projection (f32 out)
        gn_kernel<<<(MCH * HH) / 4, 256, 0, stream>>>(ryc, out, gamma, beta, cOff);
        gemm_bt<EPI_NONE, true, float><<<dim3(MCH / BM, CCH / BN), 256, 0, stream>>>(
            ryc, Wob, out, CCH, CCH, CCH, cOff);
    }
}